// Round 2
// baseline (723.675 us; speedup 1.0000x reference)
//
#include <hip/hip_runtime.h>
#include <hip/hip_bf16.h>

#define H    2048
#define NI   1408
#define NE   8
#define NTOK 2048
#define NIS  2816

typedef __bf16 bf16x8 __attribute__((ext_vector_type(8)));
typedef float  f32x4  __attribute__((ext_vector_type(4)));

#define ASYNC16(gp, lp) __builtin_amdgcn_global_load_lds( \
    (const __attribute__((address_space(1))) void*)(gp),  \
    (__attribute__((address_space(3))) void*)(lp), 16, 0, 0)

#define MFMA16 __builtin_amdgcn_mfma_f32_16x16x32_bf16

// ---------------------------------------------------------------------------
// Elementwise fp32 -> bf16 (x), 8 elems/thread
// ---------------------------------------------------------------------------
__global__ __launch_bounds__(256)
void cvt_kernel(const float* __restrict__ in, __bf16* __restrict__ out)
{
    size_t i = ((size_t)blockIdx.x * 256 + threadIdx.x) * 8;
    float4 v0 = *(const float4*)(in + i);
    float4 v1 = *(const float4*)(in + i + 4);
    union { __bf16 b[8]; uint4 u; } p;
    p.b[0] = (__bf16)v0.x; p.b[1] = (__bf16)v0.y;
    p.b[2] = (__bf16)v0.z; p.b[3] = (__bf16)v0.w;
    p.b[4] = (__bf16)v1.x; p.b[5] = (__bf16)v1.y;
    p.b[6] = (__bf16)v1.z; p.b[7] = (__bf16)v1.w;
    *(uint4*)(out + i) = p.u;
}

// ---------------------------------------------------------------------------
// Transpose-convert: in fp32 [K][N] (batched by z) -> out bf16.
// pmode = -1: plain out[n][k].
// pmode = 0/1: packed g/u interleave: out row = ((n>>7)*2+pmode)*128 + (n&127)
//              (per-z out stride 2*K*N) -> builds wguT/swguT superblocks.
// ---------------------------------------------------------------------------
__global__ __launch_bounds__(256)
void cvt_t_kernel(const float* __restrict__ in, __bf16* __restrict__ out,
                  int K, int N, int pmode)
{
    in  += (size_t)blockIdx.z * K * N;
    out += (size_t)blockIdx.z * (pmode < 0 ? (size_t)K * N : 2 * (size_t)K * N);
    const int n0 = blockIdx.x * 64;
    const int k0 = blockIdx.y * 64;
    __shared__ __bf16 tile[64][72];
    const int t = threadIdx.x;
    const int tr  = t >> 4;
    const int tc4 = (t & 15) * 4;
#pragma unroll
    for (int i = 0; i < 4; ++i) {
        int k = i * 16 + tr;
        float4 v = *(const float4*)(in + (size_t)(k0 + k) * N + n0 + tc4);
        tile[k][tc4 + 0] = (__bf16)v.x;
        tile[k][tc4 + 1] = (__bf16)v.y;
        tile[k][tc4 + 2] = (__bf16)v.z;
        tile[k][tc4 + 3] = (__bf16)v.w;
    }
    __syncthreads();
    const int n = t >> 2, q = t & 3;
#pragma unroll
    for (int hh = 0; hh < 2; ++hh) {
        int qq = q + hh * 4;
        union { __bf16 b[8]; uint4 u; } pk;
#pragma unroll
        for (int j = 0; j < 8; ++j) pk.b[j] = tile[qq * 8 + j][n];
        int gn = n0 + n;
        size_t orow = (pmode < 0) ? (size_t)gn
                    : ((size_t)((gn >> 7) * 2 + pmode) * 128 + (gn & 127));
        *(uint4*)(out + orow * K + k0 + qq * 8) = pk.u;
    }
}

// ---------------------------------------------------------------------------
// Gate: fp32 logits -> softmax -> top2 -> per-expert pair lists
// ---------------------------------------------------------------------------
__global__ __launch_bounds__(256)
void gate_kernel(const float* __restrict__ x, const float* __restrict__ gw,
                 float* __restrict__ topw, int* __restrict__ pairs,
                 int* __restrict__ cnt)
{
    int tok  = blockIdx.x * 4 + (threadIdx.x >> 6);
    int lane = threadIdx.x & 63;
    float acc[NE];
#pragma unroll
    for (int e = 0; e < NE; ++e) acc[e] = 0.f;
    const float* xr = x + (size_t)tok * H;
    for (int h = lane; h < H; h += 64) {
        float xv = xr[h];
#pragma unroll
        for (int e = 0; e < NE; ++e) acc[e] += xv * gw[e * H + h];
    }
#pragma unroll
    for (int e = 0; e < NE; ++e) {
        float v = acc[e];
        for (int off = 32; off; off >>= 1) v += __shfl_xor(v, off);
        acc[e] = v;
    }
    if (lane == 0) {
        float mx = acc[0];
#pragma unroll
        for (int e = 1; e < NE; ++e) mx = fmaxf(mx, acc[e]);
        float p[NE]; float s = 0.f;
#pragma unroll
        for (int e = 0; e < NE; ++e) { p[e] = __expf(acc[e] - mx); s += p[e]; }
        float inv = 1.f / s;
        int e1 = 0;
#pragma unroll
        for (int e = 1; e < NE; ++e) if (acc[e] > acc[e1]) e1 = e;
        int e2 = -1;
#pragma unroll
        for (int e = 0; e < NE; ++e) {
            if (e == e1) continue;
            if (e2 < 0 || acc[e] > acc[e2]) e2 = e;
        }
        topw[tok * 2 + 0] = p[e1] * inv;
        topw[tok * 2 + 1] = p[e2] * inv;
        int pos1 = atomicAdd(&cnt[e1], 1);
        pairs[e1 * NTOK + pos1] = tok * 2 + 0;
        int pos2 = atomicAdd(&cnt[e2], 1);
        pairs[e2 * NTOK + pos2] = tok * 2 + 1;
    }
}

// ---------------------------------------------------------------------------
// Merged GU GEMM -- m201-style 8-phase schedule on a fused 256x256 tile.
// B panel = packed wguT superblock [256 rows][H]: rows 0-127 = gate cols,
// rows 128-255 = up cols (same 128 output cols). Single GEMM; silu recombine
// across waves via f32 LDS overlay in the epilogue.
// BM=256, BN=256(fused), BK=64, 512 thr / 8 waves (2M x 4N), per-wave 128x64.
// Half-tile = [256][32] (16KB), double-buffered A/B = 128KB LDS.
// 4 phases per K-tile, 16 MFMA/phase; vmcnt(4) once per tile (never 0).
// ---------------------------------------------------------------------------
#define NT (H / 64)

__global__ __launch_bounds__(512, 2)
void gu_kernel(const __bf16* __restrict__ xb,
               const __bf16* __restrict__ wguT, const __bf16* __restrict__ swguT,
               __bf16* __restrict__ h_sh, __bf16* __restrict__ h_rt,
               const int* __restrict__ pairs, const int* __restrict__ cnt)
{
    const int t = threadIdx.x, lane = t & 63;
    const int wid = t >> 6;
    const int wm = wid & 1;        // 0..1 : 128-row slice
    const int wn = wid >> 1;       // 0..3 : 64-col slice of fused 256
    const int e = blockIdx.z;
    const bool routed = (e < NE);
    const int sb = blockIdx.x;     // superblock = 128 output cols
    const int m0 = blockIdx.y * 256;

    int count = NTOK;
    const __bf16* Bp;
    __bf16* outp;
    int ldO;
    if (routed) {
        if (sb >= NI / 128) return;
        count = cnt[e];
        if (m0 >= count) return;
        Bp = wguT + (size_t)e * (2 * NI * H) + (size_t)sb * 256 * H;
        outp = h_rt; ldO = NI;
    } else {
        Bp = swguT + (size_t)sb * 256 * H;
        outp = h_sh; ldO = NIS;
    }

    // LDS: A halves [buf][kk][256][32] then B halves; 128KB total.
    __shared__ __align__(16) __bf16 sm[65536];
    __shared__ int tile_pid[256];
#define AH(buf, kk) (sm + ((buf) * 2 + (kk)) * 8192)
#define BH(buf, kk) (sm + 32768 + ((buf) * 2 + (kk)) * 8192)

    if (t < 256) {
        int j = m0 + t;
        tile_pid[t] = routed ? ((j < count) ? pairs[e * NTOK + j] : -1) : j;
    }
    __syncthreads();

    // ---- staging: thread t owns stored chunk t (rows 0-127) and 512+t
    // (rows 128-255) of each 16KB half. Stored chunk c_st at row r holds
    // global chunk c_st ^ ((r>>1)&3)  -> pre-swizzled global source.
    const int sr = t >> 2;
    const int cg = (t & 3) ^ ((t >> 3) & 3);
    size_t ar0, ar1;
    if (routed) {
        int p0 = tile_pid[sr];        if (p0 < 0) p0 = 0;
        int p1 = tile_pid[128 + sr];  if (p1 < 0) p1 = 0;
        ar0 = (size_t)(p0 >> 1); ar1 = (size_t)(p1 >> 1);
    } else {
        ar0 = (size_t)(m0 + sr); ar1 = (size_t)(m0 + 128 + sr);
    }
    const __bf16* gA0 = xb + ar0 * H + cg * 8;
    const __bf16* gA1 = xb + ar1 * H + cg * 8;
    const __bf16* gB0 = Bp + (size_t)sr * H + cg * 8;
    const __bf16* gB1 = Bp + (size_t)(128 + sr) * H + cg * 8;

#define STAGE_A(T, kk, buf) do {                              \
        ASYNC16(gA0 + (T) * 64 + (kk) * 32, AH(buf, kk) + t * 8);        \
        ASYNC16(gA1 + (T) * 64 + (kk) * 32, AH(buf, kk) + 4096 + t * 8); \
    } while (0)
#define STAGE_B(T, kk, buf) do {                              \
        ASYNC16(gB0 + (T) * 64 + (kk) * 32, BH(buf, kk) + t * 8);        \
        ASYNC16(gB1 + (T) * 64 + (kk) * 32, BH(buf, kk) + 4096 + t * 8); \
    } while (0)

    // ---- fragment read offsets (swizzled chunk, per-lane constant)
    const int fr  = lane & 15;
    const int cr8 = (((lane >> 4) ^ ((fr >> 1) & 3)) << 3);
    const int aoff = (wm * 128 + fr) * 32 + cr8;   // + mi*512
    const int boff = (wn * 64  + fr) * 32 + cr8;   // + ni*512 (flat ni 0..3)

    f32x4 acc[8][4] = {};
    bf16x8 a[8], b[2];

    // ---- prologue: tile0 (all 4 halves) + tile1 k0 halves
    STAGE_A(0, 0, 0); STAGE_B(0, 0, 0);
    STAGE_A(0, 1, 0); STAGE_B(0, 1, 0);
    STAGE_A(1, 0, 1); STAGE_B(1, 0, 1);
    asm volatile("s_waitcnt vmcnt(4)" ::: "memory");   // tile0 resident
    __builtin_amdgcn_s_barrier();

#define PHASE_MFMA(NHB)                                       \
    __builtin_amdgcn_s_barrier();                             \
    asm volatile("s_waitcnt lgkmcnt(0)" ::: "memory");        \
    __builtin_amdgcn_sched_barrier(0);                        \
    __builtin_amdgcn_s_setprio(1);                            \
    _Pragma("unroll")                                         \
    for (int mi = 0; mi < 8; ++mi) {                          \
        acc[mi][(NHB) + 0] = MFMA16(a[mi], b[0], acc[mi][(NHB) + 0], 0, 0, 0); \
        acc[mi][(NHB) + 1] = MFMA16(a[mi], b[1], acc[mi][(NHB) + 1], 0, 0, 0); \
    }                                                         \
    __builtin_amdgcn_s_setprio(0);                            \
    __builtin_amdgcn_s_barrier();

#define TILE(TT, BUF) do {                                                   \
    /* phase (k0, n-half0): read a[] + b[0..1]; stage k1(TT+1) */            \
    _Pragma("unroll")                                                        \
    for (int mi = 0; mi < 8; ++mi)                                           \
        a[mi] = *(const bf16x8*)(AH(BUF, 0) + aoff + mi * 512);              \
    b[0] = *(const bf16x8*)(BH(BUF, 0) + boff);                              \
    b[1] = *(const bf16x8*)(BH(BUF, 0) + boff + 512);                        \
    if ((TT) + 1 < NT) { STAGE_A((TT) + 1, 1, (BUF) ^ 1);                    \
                         STAGE_B((TT) + 1, 1, (BUF) ^ 1); }                  \
    PHASE_MFMA(0)                                                            \
    /* phase (k0, n-half1) */                                                \
    b[0] = *(const bf16x8*)(BH(BUF, 0) + boff + 1024);                       \
    b[1] = *(const bf16x8*)(BH(BUF, 0) + boff + 1536);                       \
    PHASE_MFMA(2)                                                            \
    /* phase (k1, n-half0): stage A-k0(TT+2) into freed slot */              \
    _Pragma("unroll")                                                        \
    for (int mi = 0; mi < 8; ++mi)                                           \
        a[mi] = *(const bf16x8*)(AH(BUF, 1) + aoff + mi * 512);              \
    b[0] = *(const bf16x8*)(BH(BUF, 1) + boff);                              \
    b[1] = *(const bf16x8*)(BH(BUF, 1) + boff + 512);                        \
    if ((TT) + 2 < NT) STAGE_A((TT) + 2, 0, BUF);                            \
    PHASE_MFMA(0)                                                            \
    /* phase (k1, n-half1): stage B-k0(TT+2); counted wait, never 0 */       \
    b[0] = *(const bf16x8*)(BH(BUF, 1) + boff + 1024);                       \
    b[1] = *(const bf16x8*)(BH(BUF, 1) + boff + 1536);                       \
    if ((TT) + 2 < NT) STAGE_B((TT) + 2, 0, BUF);                            \
    if ((TT) + 2 < NT) asm volatile("s_waitcnt vmcnt(4)" ::: "memory");      \
    else               asm volatile("s_waitcnt vmcnt(0)" ::: "memory");      \
    PHASE_MFMA(2)                                                            \
} while (0)

#pragma unroll 1
    for (int tt = 0; tt < NT; tt += 2) {
        TILE(tt, 0);
        TILE(tt + 1, 1);
    }

    // ---- epilogue: u-waves (wn>=2) dump acc to f32 LDS overlay, then
    // g-waves (wn<2) compute silu(g)*u and store bf16.
    float* uls = (float*)sm;   // [256][128] f32 = 128KB, overlays A/B bufs
    if (wn >= 2) {
#pragma unroll
        for (int mi = 0; mi < 8; ++mi)
#pragma unroll
            for (int rr = 0; rr < 4; ++rr) {
                int row = wm * 128 + mi * 16 + (lane >> 4) * 4 + rr;
#pragma unroll
                for (int ni = 0; ni < 4; ++ni) {
                    int col = (wn - 2) * 64 + ni * 16 + (lane & 15);
                    uls[row * 128 + col] = acc[mi][ni][rr];
                }
            }
    }
    __syncthreads();
    if (wn < 2) {
#pragma unroll
        for (int mi = 0; mi < 8; ++mi)
#pragma unroll
            for (int rr = 0; rr < 4; ++rr) {
                int row = wm * 128 + mi * 16 + (lane >> 4) * 4 + rr;
                int pid = tile_pid[row];
                if (routed && pid < 0) continue;
                size_t orow = routed ? (size_t)pid : (size_t)(m0 + row);
#pragma unroll
                for (int ni = 0; ni < 4; ++ni) {
                    int lc = wn * 64 + ni * 16 + (lane & 15);
                    float g = acc[mi][ni][rr];
                    float u = uls[row * 128 + lc];
                    float hv = g / (1.f + __expf(-g)) * u;
                    outp[orow * (size_t)ldO + sb * 128 + lc] = (__bf16)hv;
                }
            }
    }
#undef AH
#undef BH
#undef STAGE_A
#undef STAGE_B
#undef PHASE_MFMA
#undef TILE
}

// ---------------------------------------------------------------------------
// Merged down GEMM, all-atomic epilogue into zero-initialized d_out:
//  z<NE : routed expert z: d_out[tok] += topw[pid] * (h_rt[pid] @ w_down[e])
//  z==NE: shared, K-half 0 ; z==NE+1: shared, K-half 1 (split-K, w=1)
// ---------------------------------------------------------------------------
__global__ __launch_bounds__(256, 2)
void down_kernel(const __bf16* __restrict__ h_sh, const __bf16* __restrict__ h_rt,
                 const __bf16* __restrict__ swdT, const __bf16* __restrict__ wdT,
                 float* __restrict__ out,
                 const int* __restrict__ pairs, const int* __restrict__ cnt,
                 const float* __restrict__ topw)
{
    const int t = threadIdx.x, lane = t & 63;
    const int wid = t >> 6, wm = wid >> 1, wn = wid & 1;
    const int e = blockIdx.z;
    const bool routed = (e < NE);
    const int m0 = blockIdx.y * 128, n0 = blockIdx.x * 128;

    int count = NTOK, K, lda, koff = 0;
    const __bf16 *A, *B;
    if (routed) {
        count = cnt[e];
        if (m0 >= count) return;
        A = h_rt; lda = NI; K = NI;
        B = wdT + (size_t)e * H * NI;
    } else {
        A = h_sh; lda = NIS; K = NI;          // split-K: 2816 = 2*1408
        koff = (e == NE) ? 0 : NI;
        B = swdT;
    }

    __shared__ __align__(16) __bf16 At[128 * 32], Bt[128 * 32];
    __shared__ int tile_pid[128];
    if (t < 128) {
        int j = m0 + t;
        tile_pid[t] = routed ? ((j < count) ? pairs[e * NTOK + j] : -1) : j;
    }
    __syncthreads();

    const int r = t >> 2, c = t & 3;
    size_t ar0, ar1;
    if (routed) {
        int p0 = tile_pid[r];      if (p0 < 0) p0 = 0;
        int p1 = tile_pid[r + 64]; if (p1 < 0) p1 = 0;
        ar0 = (size_t)p0; ar1 = (size_t)p1;
    } else {
        ar0 = (size_t)(m0 + r); ar1 = (size_t)(m0 + r + 64);
    }
    const __bf16* a0 = A + ar0 * lda + koff + c * 8;
    const __bf16* a1 = A + ar1 * lda + koff + c * 8;
    const __bf16* b0 = B + (size_t)(n0 + r) * lda + koff + c * 8;
    const __bf16* b1 = B + (size_t)(n0 + r + 64) * lda + koff + c * 8;
    __bf16* lA0 = At + t * 8;  __bf16* lA1 = At + (256 + t) * 8;
    __bf16* lB0 = Bt + t * 8;  __bf16* lB1 = Bt + (256 + t) * 8;

    f32x4 acc[4][4] = {};

    for (int k0 = 0; k0 < K; k0 += 32) {
        __syncthreads();
        ASYNC16(a0 + k0, lA0); ASYNC16(a1 + k0, lA1);
        ASYNC16(b0 + k0, lB0); ASYNC16(b1 + k0, lB1);
        __syncthreads();
        bf16x8 a[4];
#pragma unroll
        for (int mi = 0; mi < 4; ++mi)
            a[mi] = *(const bf16x8*)(At + (wm * 64 + mi * 16 + (lane & 15)) * 32 + (lane >> 4) * 8);
#pragma unroll
        for (int ni = 0; ni < 4; ++ni) {
            bf16x8 b = *(const bf16x8*)(Bt + (wn * 64 + ni * 16 + (lane & 15)) * 32 + (lane >> 4) * 8);
#pragma unroll
            for (int mi = 0; mi < 4; ++mi)
                acc[mi][ni] = __builtin_amdgcn_mfma_f32_16x16x32_bf16(a[mi], b, acc[mi][ni], 0, 0, 0);
        }
    }

#pragma unroll
    for (int mi = 0; mi < 4; ++mi) {
#pragma unroll
        for (int rr = 0; rr < 4; ++rr) {
            int row = wm * 64 + mi * 16 + (lane >> 4) * 4 + rr;
            int pid = tile_pid[row];
            if (routed && pid < 0) continue;
            size_t tok; float w;
            if (routed) { tok = (size_t)(pid >> 1); w = topw[pid]; }
            else        { tok = (size_t)(m0 + row); w = 1.f; }
#pragma unroll
            for (int ni = 0; ni < 4; ++ni) {
                int col = n0 + wn * 64 + ni * 16 + (lane & 15);
                atomicAdd(out + tok * H + col, w * acc[mi][ni][rr]);
            }
        }
    }
}

// ---------------------------------------------------------------------------
extern "C" void kernel_launch(void* const* d_in, const int* in_sizes, int n_in,
                              void* d_out, int out_size, void* d_ws, size_t ws_size,
                              hipStream_t stream)
{
    const float* x       = (const float*)d_in[0];
    const float* gate_w  = (const float*)d_in[1];
    const float* w_gate  = (const float*)d_in[2];
    const float* w_up    = (const float*)d_in[3];
    const float* w_down  = (const float*)d_in[4];
    const float* sw_gate = (const float*)d_in[5];
    const float* sw_up   = (const float*)d_in[6];
    const float* sw_down = (const float*)d_in[7];

    // workspace layout (158.5 MB total)
    char*   ws    = (char*)d_ws;
    float*  topw  = (float*)ws;                          // 16 KB
    int*    cnt   = (int*)(ws + 16384);                  // 128 B
    int*    pairs = (int*)(ws + 16512);                  // 64 KB
    __bf16* xb    = (__bf16*)(ws + 131072);              // 8.39 MB
    __bf16* h_sh  = (__bf16*)(ws + 8519680);             // 11.53 MB
    __bf16* h_rt  = (__bf16*)(ws + 20054016);            // 11.53 MB
    __bf16* swguT = (__bf16*)(ws + 31588352);            // 23.07 MB (packed g|u)
    __bf16* swdT  = (__bf16*)(ws + 54657024);            // 11.53 MB
    __bf16* wguT  = (__bf16*)(ws + 66191360);            // 92.27 MB (packed g|u)
    __bf16* wdT   = wguT;  // aliased: converted AFTER gu_kernel consumed wguT

    hipMemsetAsync(cnt, 0, NE * sizeof(int), stream);
    hipMemsetAsync(d_out, 0, (size_t)NTOK * H * sizeof(float), stream);

    // fp32 -> bf16 (+transpose; g/u weights packed into 256-row superblocks)
    cvt_kernel<<<NTOK * H / 2048, 256, 0, stream>>>(x, xb);
    cvt_t_kernel<<<dim3(NIS / 64, H / 64, 1), 256, 0, stream>>>(sw_gate, swguT, H, NIS, 0);
    cvt_t_kernel<<<dim3(NIS / 64, H / 64, 1), 256, 0, stream>>>(sw_up,   swguT, H, NIS, 1);
    cvt_t_kernel<<<dim3(H / 64, NIS / 64, 1), 256, 0, stream>>>(sw_down, swdT, NIS, H, -1);
    cvt_t_kernel<<<dim3(NI / 64, H / 64, NE), 256, 0, stream>>>(w_gate,  wguT, H, NI, 0);
    cvt_t_kernel<<<dim3(NI / 64, H / 64, NE), 256, 0, stream>>>(w_up,    wguT, H, NI, 1);

    gate_kernel<<<NTOK / 4, 256, 0, stream>>>(x, gate_w, topw, pairs, cnt);

    // merged GU (8-phase schedule): z=0..7 routed, z=8 shared
    gu_kernel<<<dim3(NIS / 128, NTOK / 256, NE + 1), 512, 0, stream>>>(
        xb, wguT, swguT, h_sh, h_rt, pairs, cnt);

    // convert w_down now (aliases wguT region, safe after gu_kernel)
    cvt_t_kernel<<<dim3(H / 64, NI / 64, NE), 256, 0, stream>>>(w_down, wdT, NI, H, -1);

    // merged down: z=0..7 routed (atomic, weighted), z=8,9 shared split-K
    down_kernel<<<dim3(H / 128, NTOK / 128, NE + 2), 256, 0, stream>>>(
        h_sh, h_rt, swdT, wdT, (float*)d_out, pairs, cnt, topw);
}

// Round 3
// 698.796 us; speedup vs baseline: 1.0356x; 1.0356x over previous
//
#include <hip/hip_runtime.h>
#include <hip/hip_bf16.h>

#define H    2048
#define NI   1408
#define NE   8
#define NTOK 2048
#define NIS  2816

typedef __bf16 bf16x8 __attribute__((ext_vector_type(8)));
typedef float  f32x4  __attribute__((ext_vector_type(4)));

#define ASYNC16(gp, lp) __builtin_amdgcn_global_load_lds( \
    (const __attribute__((address_space(1))) void*)(gp),  \
    (__attribute__((address_space(3))) void*)(lp), 16, 0, 0)

#define MFMA16 __builtin_amdgcn_mfma_f32_16x16x32_bf16

// ---------------------------------------------------------------------------
// Elementwise fp32 -> bf16 (x), 8 elems/thread
// ---------------------------------------------------------------------------
__global__ __launch_bounds__(256)
void cvt_kernel(const float* __restrict__ in, __bf16* __restrict__ out)
{
    size_t i = ((size_t)blockIdx.x * 256 + threadIdx.x) * 8;
    float4 v0 = *(const float4*)(in + i);
    float4 v1 = *(const float4*)(in + i + 4);
    union { __bf16 b[8]; uint4 u; } p;
    p.b[0] = (__bf16)v0.x; p.b[1] = (__bf16)v0.y;
    p.b[2] = (__bf16)v0.z; p.b[3] = (__bf16)v0.w;
    p.b[4] = (__bf16)v1.x; p.b[5] = (__bf16)v1.y;
    p.b[6] = (__bf16)v1.z; p.b[7] = (__bf16)v1.w;
    *(uint4*)(out + i) = p.u;
}

// ---------------------------------------------------------------------------
// Transpose-convert: in fp32 [K][N] (batched by z) -> out bf16 [N][K]
// ---------------------------------------------------------------------------
__global__ __launch_bounds__(256)
void cvt_t_kernel(const float* __restrict__ in, __bf16* __restrict__ out,
                  int K, int N)
{
    const size_t zoff = (size_t)blockIdx.z * K * N;
    in  += zoff;
    out += zoff;
    const int n0 = blockIdx.x * 64;
    const int k0 = blockIdx.y * 64;
    __shared__ __bf16 tile[64][72];
    const int t = threadIdx.x;
    const int tr  = t >> 4;
    const int tc4 = (t & 15) * 4;
#pragma unroll
    for (int i = 0; i < 4; ++i) {
        int k = i * 16 + tr;
        float4 v = *(const float4*)(in + (size_t)(k0 + k) * N + n0 + tc4);
        tile[k][tc4 + 0] = (__bf16)v.x;
        tile[k][tc4 + 1] = (__bf16)v.y;
        tile[k][tc4 + 2] = (__bf16)v.z;
        tile[k][tc4 + 3] = (__bf16)v.w;
    }
    __syncthreads();
    const int n = t >> 2, q = t & 3;
#pragma unroll
    for (int hh = 0; hh < 2; ++hh) {
        int qq = q + hh * 4;
        union { __bf16 b[8]; uint4 u; } pk;
#pragma unroll
        for (int j = 0; j < 8; ++j) pk.b[j] = tile[qq * 8 + j][n];
        *(uint4*)(out + (size_t)(n0 + n) * K + k0 + qq * 8) = pk.u;
    }
}

// ---------------------------------------------------------------------------
// Gate: fp32 logits -> softmax -> top2 -> per-expert pair lists
// ---------------------------------------------------------------------------
__global__ __launch_bounds__(256)
void gate_kernel(const float* __restrict__ x, const float* __restrict__ gw,
                 float* __restrict__ topw, int* __restrict__ pairs,
                 int* __restrict__ cnt)
{
    int tok  = blockIdx.x * 4 + (threadIdx.x >> 6);
    int lane = threadIdx.x & 63;
    float acc[NE];
#pragma unroll
    for (int e = 0; e < NE; ++e) acc[e] = 0.f;
    const float* xr = x + (size_t)tok * H;
    for (int h = lane; h < H; h += 64) {
        float xv = xr[h];
#pragma unroll
        for (int e = 0; e < NE; ++e) acc[e] += xv * gw[e * H + h];
    }
#pragma unroll
    for (int e = 0; e < NE; ++e) {
        float v = acc[e];
        for (int off = 32; off; off >>= 1) v += __shfl_xor(v, off);
        acc[e] = v;
    }
    if (lane == 0) {
        float mx = acc[0];
#pragma unroll
        for (int e = 1; e < NE; ++e) mx = fmaxf(mx, acc[e]);
        float p[NE]; float s = 0.f;
#pragma unroll
        for (int e = 0; e < NE; ++e) { p[e] = __expf(acc[e] - mx); s += p[e]; }
        float inv = 1.f / s;
        int e1 = 0;
#pragma unroll
        for (int e = 1; e < NE; ++e) if (acc[e] > acc[e1]) e1 = e;
        int e2 = -1;
#pragma unroll
        for (int e = 0; e < NE; ++e) {
            if (e == e1) continue;
            if (e2 < 0 || acc[e] > acc[e2]) e2 = e;
        }
        topw[tok * 2 + 0] = p[e1] * inv;
        topw[tok * 2 + 1] = p[e2] * inv;
        int pos1 = atomicAdd(&cnt[e1], 1);
        pairs[e1 * NTOK + pos1] = tok * 2 + 0;
        int pos2 = atomicAdd(&cnt[e2], 1);
        pairs[e2 * NTOK + pos2] = tok * 2 + 1;
    }
}

// ---------------------------------------------------------------------------
// Merged GU GEMM: z<NE -> routed expert z (gathered rows, out h_rt[pid]);
//                 z==NE -> shared expert (out h_sh).
// C = silu(A@Bg^T) * (A@Bu^T). 128x128x32 tile, 4 waves, 2 blocks/CU.
// Double-buffered LDS (2-phase): stage tile t+1 before computing tile t;
// single __syncthreads per K-step (its vmcnt(0) drain hides under compute).
// XOR chunk-swizzle both-sides (pre-swizzled global src, swizzled ds_read)
// -> 0 LDS bank conflicts (verified round 1).
// ---------------------------------------------------------------------------
__global__ __launch_bounds__(256, 2)
void gu_kernel(const __bf16* __restrict__ xb,
               const __bf16* __restrict__ wgT, const __bf16* __restrict__ wuT,
               const __bf16* __restrict__ swgT, const __bf16* __restrict__ swuT,
               __bf16* __restrict__ h_sh, __bf16* __restrict__ h_rt,
               const int* __restrict__ pairs, const int* __restrict__ cnt)
{
    const int t = threadIdx.x, lane = t & 63;
    const int wid = t >> 6, wm = wid >> 1, wn = wid & 1;
    const int e = blockIdx.z;
    const bool routed = (e < NE);
    const int m0 = blockIdx.y * 128, n0 = blockIdx.x * 128;

    int count = NTOK;
    const __bf16 *Bg, *Bu;
    __bf16* outp;
    int ldO;
    if (routed) {
        if (n0 >= NI) return;
        count = cnt[e];
        if (m0 >= count) return;
        Bg = wgT + (size_t)e * NI * H;
        Bu = wuT + (size_t)e * NI * H;
        outp = h_rt; ldO = NI;
    } else {
        Bg = swgT; Bu = swuT; outp = h_sh; ldO = NIS;
    }

    // double-buffered: each array 2 x [128][32] bf16 (8KB per buf)
    __shared__ __align__(16) __bf16 At[2 * 4096], Btg[2 * 4096], Btu[2 * 4096];
    __shared__ int tile_pid[128];
    if (t < 128) {
        int j = m0 + t;
        tile_pid[t] = routed ? ((j < count) ? pairs[e * NTOK + j] : -1) : j;
    }
    __syncthreads();

    // staging: thread t owns stored chunk (row = t>>2, c_st = t&3).
    // Stored chunk c_st at row r holds global chunk c_st ^ ((r>>1)&3)
    // -> pre-swizzled global source (global_load_lds dest stays linear).
    const int r = t >> 2;
    const int cg = (t & 3) ^ ((t >> 3) & 3);
    size_t ar0, ar1;
    if (routed) {
        int p0 = tile_pid[r];      if (p0 < 0) p0 = 0;
        int p1 = tile_pid[r + 64]; if (p1 < 0) p1 = 0;
        ar0 = (size_t)(p0 >> 1); ar1 = (size_t)(p1 >> 1);
    } else {
        ar0 = (size_t)(m0 + r); ar1 = (size_t)(m0 + r + 64);
    }
    const __bf16* a0 = xb + ar0 * H + cg * 8;
    const __bf16* a1 = xb + ar1 * H + cg * 8;
    const __bf16* g0 = Bg + (size_t)(n0 + r) * H + cg * 8;
    const __bf16* g1 = Bg + (size_t)(n0 + r + 64) * H + cg * 8;
    const __bf16* u0 = Bu + (size_t)(n0 + r) * H + cg * 8;
    const __bf16* u1 = Bu + (size_t)(n0 + r + 64) * H + cg * 8;

#define STAGE_GU(k, bo) do {                              \
        ASYNC16(a0 + (k), At  + (bo) + t * 8);            \
        ASYNC16(a1 + (k), At  + (bo) + 2048 + t * 8);     \
        ASYNC16(g0 + (k), Btg + (bo) + t * 8);            \
        ASYNC16(g1 + (k), Btg + (bo) + 2048 + t * 8);     \
        ASYNC16(u0 + (k), Btu + (bo) + t * 8);            \
        ASYNC16(u1 + (k), Btu + (bo) + 2048 + t * 8);     \
    } while (0)

    // fragment read offsets (swizzled chunk; per-lane constant)
    const int fr  = lane & 15;
    const int cr8 = (((lane >> 4) ^ ((fr >> 1) & 3)) << 3);

    f32x4 accg[4][4] = {};
    f32x4 accu[4][4] = {};

    STAGE_GU(0, 0);
    __syncthreads();            // drains vmcnt(0): tile 0 resident

    int bo = 0;
    for (int k0 = 0; k0 < H; k0 += 32) {
        if (k0 + 32 < H) STAGE_GU(k0 + 32, bo ^ 4096);
        bf16x8 a[4];
#pragma unroll
        for (int mi = 0; mi < 4; ++mi)
            a[mi] = *(const bf16x8*)(At + bo + (wm * 64 + mi * 16 + fr) * 32 + cr8);
#pragma unroll
        for (int ni = 0; ni < 4; ++ni) {
            bf16x8 bg = *(const bf16x8*)(Btg + bo + (wn * 64 + ni * 16 + fr) * 32 + cr8);
            bf16x8 bu = *(const bf16x8*)(Btu + bo + (wn * 64 + ni * 16 + fr) * 32 + cr8);
#pragma unroll
            for (int mi = 0; mi < 4; ++mi) {
                accg[mi][ni] = MFMA16(a[mi], bg, accg[mi][ni], 0, 0, 0);
                accu[mi][ni] = MFMA16(a[mi], bu, accu[mi][ni], 0, 0, 0);
            }
        }
        __syncthreads();        // barrier + vmcnt(0): next tile staged, reads done
        bo ^= 4096;
    }
#undef STAGE_GU

#pragma unroll
    for (int mi = 0; mi < 4; ++mi) {
#pragma unroll
        for (int rr = 0; rr < 4; ++rr) {
            int row = wm * 64 + mi * 16 + (lane >> 4) * 4 + rr;
            int pid = tile_pid[row];
            if (routed && pid < 0) continue;
            size_t orow = routed ? (size_t)pid : (size_t)(m0 + row);
#pragma unroll
            for (int ni = 0; ni < 4; ++ni) {
                int col = n0 + wn * 64 + ni * 16 + (lane & 15);
                float g = accg[mi][ni][rr];
                float u = accu[mi][ni][rr];
                float hv = g / (1.f + __expf(-g)) * u;
                outp[orow * (size_t)ldO + col] = (__bf16)hv;
            }
        }
    }
}

// ---------------------------------------------------------------------------
// Shared-expert down GEMM: d_out[tok] = h_sh[tok] @ sw_down  (full K=2816,
// plain f32 stores -> d_out needs no memset; runs BEFORE routed atomics).
// Same 2-phase double-buffered structure.
// ---------------------------------------------------------------------------
__global__ __launch_bounds__(256, 2)
void down_sh_kernel(const __bf16* __restrict__ h_sh, const __bf16* __restrict__ swdT,
                    float* __restrict__ out)
{
    const int t = threadIdx.x, lane = t & 63;
    const int wid = t >> 6, wm = wid >> 1, wn = wid & 1;
    const int m0 = blockIdx.y * 128, n0 = blockIdx.x * 128;

    __shared__ __align__(16) __bf16 At[2 * 4096], Bt[2 * 4096];

    const int r = t >> 2;
    const int cg = (t & 3) ^ ((t >> 3) & 3);
    const __bf16* a0 = h_sh + (size_t)(m0 + r) * NIS + cg * 8;
    const __bf16* a1 = h_sh + (size_t)(m0 + r + 64) * NIS + cg * 8;
    const __bf16* b0 = swdT + (size_t)(n0 + r) * NIS + cg * 8;
    const __bf16* b1 = swdT + (size_t)(n0 + r + 64) * NIS + cg * 8;

#define STAGE_D(k, bo) do {                               \
        ASYNC16(a0 + (k), At + (bo) + t * 8);             \
        ASYNC16(a1 + (k), At + (bo) + 2048 + t * 8);      \
        ASYNC16(b0 + (k), Bt + (bo) + t * 8);             \
        ASYNC16(b1 + (k), Bt + (bo) + 2048 + t * 8);      \
    } while (0)

    const int fr  = lane & 15;
    const int cr8 = (((lane >> 4) ^ ((fr >> 1) & 3)) << 3);

    f32x4 acc[4][4] = {};

    STAGE_D(0, 0);
    __syncthreads();

    int bo = 0;
    for (int k0 = 0; k0 < NIS; k0 += 32) {
        if (k0 + 32 < NIS) STAGE_D(k0 + 32, bo ^ 4096);
        bf16x8 a[4];
#pragma unroll
        for (int mi = 0; mi < 4; ++mi)
            a[mi] = *(const bf16x8*)(At + bo + (wm * 64 + mi * 16 + fr) * 32 + cr8);
#pragma unroll
        for (int ni = 0; ni < 4; ++ni) {
            bf16x8 b = *(const bf16x8*)(Bt + bo + (wn * 64 + ni * 16 + fr) * 32 + cr8);
#pragma unroll
            for (int mi = 0; mi < 4; ++mi)
                acc[mi][ni] = MFMA16(a[mi], b, acc[mi][ni], 0, 0, 0);
        }
        __syncthreads();
        bo ^= 4096;
    }

#pragma unroll
    for (int mi = 0; mi < 4; ++mi) {
#pragma unroll
        for (int rr = 0; rr < 4; ++rr) {
            int row = wm * 64 + mi * 16 + (lane >> 4) * 4 + rr;
#pragma unroll
            for (int ni = 0; ni < 4; ++ni) {
                int col = n0 + wn * 64 + ni * 16 + (lane & 15);
                out[(size_t)(m0 + row) * H + col] = acc[mi][ni][rr];
            }
        }
    }
}

// ---------------------------------------------------------------------------
// Routed down GEMM: d_out[tok] += topw[pid] * (h_rt[pid] @ w_down[e]),
// atomicAdd epilogue (runs after down_sh wrote the shared result).
// ---------------------------------------------------------------------------
__global__ __launch_bounds__(256, 2)
void down_rt_kernel(const __bf16* __restrict__ h_rt, const __bf16* __restrict__ wdT,
                    float* __restrict__ out,
                    const int* __restrict__ pairs, const int* __restrict__ cnt,
                    const float* __restrict__ topw)
{
    const int t = threadIdx.x, lane = t & 63;
    const int wid = t >> 6, wm = wid >> 1, wn = wid & 1;
    const int e = blockIdx.z;
    const int m0 = blockIdx.y * 128, n0 = blockIdx.x * 128;

    const int count = cnt[e];
    if (m0 >= count) return;
    const __bf16* B = wdT + (size_t)e * H * NI;

    __shared__ __align__(16) __bf16 At[2 * 4096], Bt[2 * 4096];
    __shared__ int tile_pid[128];
    if (t < 128) {
        int j = m0 + t;
        tile_pid[t] = (j < count) ? pairs[e * NTOK + j] : -1;
    }
    __syncthreads();

    const int r = t >> 2;
    const int cg = (t & 3) ^ ((t >> 3) & 3);
    int p0 = tile_pid[r];      if (p0 < 0) p0 = 0;
    int p1 = tile_pid[r + 64]; if (p1 < 0) p1 = 0;
    const __bf16* a0 = h_rt + (size_t)p0 * NI + cg * 8;
    const __bf16* a1 = h_rt + (size_t)p1 * NI + cg * 8;
    const __bf16* b0 = B + (size_t)(n0 + r) * NI + cg * 8;
    const __bf16* b1 = B + (size_t)(n0 + r + 64) * NI + cg * 8;

    const int fr  = lane & 15;
    const int cr8 = (((lane >> 4) ^ ((fr >> 1) & 3)) << 3);

    f32x4 acc[4][4] = {};

    STAGE_D(0, 0);
    __syncthreads();

    int bo = 0;
    for (int k0 = 0; k0 < NI; k0 += 32) {
        if (k0 + 32 < NI) STAGE_D(k0 + 32, bo ^ 4096);
        bf16x8 a[4];
#pragma unroll
        for (int mi = 0; mi < 4; ++mi)
            a[mi] = *(const bf16x8*)(At + bo + (wm * 64 + mi * 16 + fr) * 32 + cr8);
#pragma unroll
        for (int ni = 0; ni < 4; ++ni) {
            bf16x8 b = *(const bf16x8*)(Bt + bo + (wn * 64 + ni * 16 + fr) * 32 + cr8);
#pragma unroll
            for (int mi = 0; mi < 4; ++mi)
                acc[mi][ni] = MFMA16(a[mi], b, acc[mi][ni], 0, 0, 0);
        }
        __syncthreads();
        bo ^= 4096;
    }
#undef STAGE_D

#pragma unroll
    for (int mi = 0; mi < 4; ++mi) {
#pragma unroll
        for (int rr = 0; rr < 4; ++rr) {
            int row = wm * 64 + mi * 16 + (lane >> 4) * 4 + rr;
            int pid = tile_pid[row];
            if (pid < 0) continue;
            size_t tok = (size_t)(pid >> 1);
            float w = topw[pid];
#pragma unroll
            for (int ni = 0; ni < 4; ++ni) {
                int col = n0 + wn * 64 + ni * 16 + (lane & 15);
                atomicAdd(out + tok * H + col, w * acc[mi][ni][rr]);
            }
        }
    }
}

// ---------------------------------------------------------------------------
extern "C" void kernel_launch(void* const* d_in, const int* in_sizes, int n_in,
                              void* d_out, int out_size, void* d_ws, size_t ws_size,
                              hipStream_t stream)
{
    const float* x       = (const float*)d_in[0];
    const float* gate_w  = (const float*)d_in[1];
    const float* w_gate  = (const float*)d_in[2];
    const float* w_up    = (const float*)d_in[3];
    const float* w_down  = (const float*)d_in[4];
    const float* sw_gate = (const float*)d_in[5];
    const float* sw_up   = (const float*)d_in[6];
    const float* sw_down = (const float*)d_in[7];

    // workspace layout (158.5 MB total)
    char*   ws    = (char*)d_ws;
    float*  topw  = (float*)ws;                          // 16 KB
    int*    cnt   = (int*)(ws + 16384);                  // 128 B
    int*    pairs = (int*)(ws + 16512);                  // 64 KB
    __bf16* xb    = (__bf16*)(ws + 131072);              // 8.39 MB
    __bf16* h_sh  = (__bf16*)(ws + 8519680);             // 11.53 MB
    __bf16* h_rt  = (__bf16*)(ws + 20054016);            // 11.53 MB
    __bf16* swgT  = (__bf16*)(ws + 31588352);            // 11.53 MB
    __bf16* swuT  = (__bf16*)(ws + 43122688);            // 11.53 MB
    __bf16* swdT  = (__bf16*)(ws + 54657024);            // 11.53 MB
    __bf16* wgT   = (__bf16*)(ws + 66191360);            // 46.14 MB
    __bf16* wuT   = (__bf16*)(ws + 112328704);           // 46.14 MB
    __bf16* wdT   = wgT;  // aliased: converted AFTER gu_kernel finished with wgT

    hipMemsetAsync(cnt, 0, NE * sizeof(int), stream);
    // no d_out memset: down_sh_kernel plain-stores every element first

    // fp32 -> bf16 (+transpose for weights)
    cvt_kernel<<<NTOK * H / 2048, 256, 0, stream>>>(x, xb);
    cvt_t_kernel<<<dim3(NIS / 64, H / 64, 1), 256, 0, stream>>>(sw_gate, swgT, H, NIS);
    cvt_t_kernel<<<dim3(NIS / 64, H / 64, 1), 256, 0, stream>>>(sw_up,   swuT, H, NIS);
    cvt_t_kernel<<<dim3(H / 64, NIS / 64, 1), 256, 0, stream>>>(sw_down, swdT, NIS, H);
    cvt_t_kernel<<<dim3(NI / 64, H / 64, NE), 256, 0, stream>>>(w_gate,  wgT,  H, NI);
    cvt_t_kernel<<<dim3(NI / 64, H / 64, NE), 256, 0, stream>>>(w_up,    wuT,  H, NI);

    gate_kernel<<<NTOK / 4, 256, 0, stream>>>(x, gate_w, topw, pairs, cnt);

    // merged GU: z=0..7 routed, z=8 shared
    gu_kernel<<<dim3(NIS / 128, NTOK / 128, NE + 1), 256, 0, stream>>>(
        xb, wgT, wuT, swgT, swuT, h_sh, h_rt, pairs, cnt);

    // shared down first (plain stores define d_out)
    down_sh_kernel<<<dim3(H / 128, NTOK / 128, 1), 256, 0, stream>>>(
        h_sh, swdT, (float*)d_out);

    // convert w_down now (aliases wgT region, safe after gu_kernel)
    cvt_t_kernel<<<dim3(H / 64, NI / 64, NE), 256, 0, stream>>>(w_down, wdT, NI, H);

    // routed down: atomicAdd on top of shared result
    down_rt_kernel<<<dim3(H / 128, NTOK / 128, NE), 256, 0, stream>>>(
        h_rt, wdT, (float*)d_out, pairs, cnt, topw);
}